// Round 1
// baseline (1059.303 us; speedup 1.0000x reference)
//
#include <hip/hip_runtime.h>
#include <cmath>

#define EMB 256
#define HID 256
#define NHEAD 8
#define HD 32
#define A_LEN 512
#define BU_N 64
#define TOK (BU_N * A_LEN)   // 32768 tokens
#define TPB 16               // tokens per block in GEMM-ish kernels

__device__ __forceinline__ float dot4(float4 a, float4 b) {
    return a.x * b.x + a.y * b.y + a.z * b.z + a.w * b.w;
}

// ---------------------------------------------------------------------------
// Kernel 1: weight_norm(dim=0): W[r] = g[r] * v[r] / ||v[r]||, rows of 256.
// One wave per row.
// ---------------------------------------------------------------------------
__global__ __launch_bounds__(64) void wnorm_kernel(const float* __restrict__ v,
                                                   const float* __restrict__ g,
                                                   float* __restrict__ W) {
    int r = blockIdx.x;
    int lane = threadIdx.x;
    const float4* vr = (const float4*)(v + (size_t)r * 256);
    float4 x = vr[lane];                       // 64 lanes * 4 = 256 cols
    float ss = x.x * x.x + x.y * x.y + x.z * x.z + x.w * x.w;
#pragma unroll
    for (int off = 32; off >= 1; off >>= 1) ss += __shfl_xor(ss, off);
    float sc = g[r] * rsqrtf(ss);
    float4 o;
    o.x = x.x * sc; o.y = x.y * sc; o.z = x.z * sc; o.w = x.w * sc;
    ((float4*)(W + (size_t)r * 256))[lane] = o;
}

// ---------------------------------------------------------------------------
// Kernel 2: LN1 + QKV GEMM + bias + RoPE + scatter to head-major q/k/v.
// Block = 256 threads, 16 tokens. Each thread owns weight rows {tid, tid+256,
// tid+512} (streamed as full 64B lines); xn tokens broadcast from LDS.
// ---------------------------------------------------------------------------
__global__ __launch_bounds__(256) void ln_qkv_rope_kernel(
    const float* __restrict__ z, const float* __restrict__ ln_g,
    const float* __restrict__ ln_b, const float* __restrict__ Wqkv,
    const float* __restrict__ pb, float* __restrict__ qb,
    float* __restrict__ kb, float* __restrict__ vb) {
    __shared__ float xn[TPB][EMB];        // 16 KB
    __shared__ float st[TPB][3 * HID];    // 48 KB
    int tid = threadIdx.x;
    int t0 = blockIdx.x * TPB;

    // ---- Phase A: LayerNorm (16 lanes per token row) ----
    {
        int row = tid >> 4, sub = tid & 15;
        const float4* zr = (const float4*)(z + (size_t)(t0 + row) * EMB + sub * 16);
        float4 v0 = zr[0], v1 = zr[1], v2 = zr[2], v3 = zr[3];
        float s = v0.x + v0.y + v0.z + v0.w + v1.x + v1.y + v1.z + v1.w +
                  v2.x + v2.y + v2.z + v2.w + v3.x + v3.y + v3.z + v3.w;
        float ss = dot4(v0, v0) + dot4(v1, v1) + dot4(v2, v2) + dot4(v3, v3);
#pragma unroll
        for (int off = 8; off >= 1; off >>= 1) {
            s += __shfl_xor(s, off);
            ss += __shfl_xor(ss, off);
        }
        float mu = s * (1.0f / EMB);
        float inv = rsqrtf(ss * (1.0f / EMB) - mu * mu + 1e-5f);
        float vals[16];
        ((float4*)vals)[0] = v0; ((float4*)vals)[1] = v1;
        ((float4*)vals)[2] = v2; ((float4*)vals)[3] = v3;
        int cb = sub * 16;
#pragma unroll
        for (int i = 0; i < 16; i++)
            xn[row][cb + i] = (vals[i] - mu) * inv * ln_g[cb + i] + ln_b[cb + i];
    }
    __syncthreads();

    // ---- Phase B: GEMM, 3 rows x 16 tokens per thread ----
    float acc[3][TPB];
#pragma unroll
    for (int r = 0; r < 3; r++)
#pragma unroll
        for (int t = 0; t < TPB; t++) acc[r][t] = 0.f;

    for (int k = 0; k < EMB; k += 16) {
        float4 w[3][4];
#pragma unroll
        for (int r = 0; r < 3; r++) {
            const float4* wp = (const float4*)(Wqkv + (size_t)(tid + r * 256) * EMB + k);
            w[r][0] = wp[0]; w[r][1] = wp[1]; w[r][2] = wp[2]; w[r][3] = wp[3];
        }
#pragma unroll
        for (int tok = 0; tok < TPB; tok++) {
            const float4* xp = (const float4*)&xn[tok][k];
            float4 x0 = xp[0], x1 = xp[1], x2 = xp[2], x3 = xp[3];
#pragma unroll
            for (int r = 0; r < 3; r++)
                acc[r][tok] += dot4(w[r][0], x0) + dot4(w[r][1], x1) +
                               dot4(w[r][2], x2) + dot4(w[r][3], x3);
        }
    }

#pragma unroll
    for (int r = 0; r < 3; r++) {
        float bias = pb[tid + r * 256];
#pragma unroll
        for (int tok = 0; tok < TPB; tok++)
            st[tok][tid + r * 256] = acc[r][tok] + bias;
    }
    __syncthreads();

    // ---- Phase C: RoPE + scatter ----
    for (int it = 0; it < 48; it++) {
        int tok = it / 3;
        int c = (it - tok * 3) * 256 + tid;
        int h = c / 96;
        int cc = c - h * 96;
        int t = t0 + tok;
        int bu = t >> 9;
        int a = t & 511;
        float val = st[tok][c];
        size_t hb = (((size_t)(bu * NHEAD + h)) * A_LEN + a) * HD;
        if (cc < 64) {
            int d = cc & 31;                 // dim within head
            float part = st[tok][c ^ 1];     // rope partner
            int i2 = d & ~1;                 // 2*(d/2)
            float freq = __expf(-(float)i2 * (9.210340371976184f / 32.0f));
            float ang = (float)a * freq;
            float cs = cosf(ang), sn = sinf(ang);
            float outv = ((d & 1) == 0) ? (val * cs - part * sn)
                                        : (val * cs + part * sn);
            float* dst = (cc < 32) ? qb : kb;
            dst[hb + d] = outv;
        } else {
            vb[hb + (cc - 64)] = val;
        }
    }
}

// ---------------------------------------------------------------------------
// Kernel 3: attention per (bu,h). 512 threads = 1 query each. Online softmax,
// K/V tiles (128 keys) staged in LDS, broadcast reads.
// ---------------------------------------------------------------------------
__global__ __launch_bounds__(512) void attn_kernel(const float* __restrict__ qb,
                                                   const float* __restrict__ kb,
                                                   const float* __restrict__ vb,
                                                   float* __restrict__ ob) {
    __shared__ float Ks[128 * HD];   // 16 KB
    __shared__ float Vs[128 * HD];   // 16 KB
    int tid = threadIdx.x;
    int bh = blockIdx.x;
    const float* qp = qb + (size_t)bh * (A_LEN * HD);
    const float* kp = kb + (size_t)bh * (A_LEN * HD);
    const float* vp = vb + (size_t)bh * (A_LEN * HD);

    const float SCALE = 0.17677669529663687f;   // 1/sqrt(32)
    float q[HD];
    {
        const float4* qq = (const float4*)(qp + (size_t)tid * HD);
#pragma unroll
        for (int i = 0; i < 8; i++) {
            float4 t4 = qq[i];
            q[4 * i + 0] = t4.x * SCALE; q[4 * i + 1] = t4.y * SCALE;
            q[4 * i + 2] = t4.z * SCALE; q[4 * i + 3] = t4.w * SCALE;
        }
    }
    float m = -1e30f, l = 0.f;
    float acc[HD];
#pragma unroll
    for (int d = 0; d < HD; d++) acc[d] = 0.f;

    for (int kt = 0; kt < 4; kt++) {
        __syncthreads();
        const float4* ksrc = (const float4*)(kp + (size_t)kt * 128 * HD);
        const float4* vsrc = (const float4*)(vp + (size_t)kt * 128 * HD);
        for (int i = tid; i < 1024; i += 512) {
            ((float4*)Ks)[i] = ksrc[i];
            ((float4*)Vs)[i] = vsrc[i];
        }
        __syncthreads();
        for (int j = 0; j < 128; j++) {
            const float4* kj = (const float4*)&Ks[j * HD];
            float s = 0.f;
#pragma unroll
            for (int i = 0; i < 8; i++) {
                float4 k4 = kj[i];
                s += q[4 * i + 0] * k4.x + q[4 * i + 1] * k4.y +
                     q[4 * i + 2] * k4.z + q[4 * i + 3] * k4.w;
            }
            if (s > m) {
                float sc = __expf(m - s);
                l *= sc;
#pragma unroll
                for (int d = 0; d < HD; d++) acc[d] *= sc;
                m = s;
            }
            float p = __expf(s - m);
            l += p;
            const float4* vj = (const float4*)&Vs[j * HD];
#pragma unroll
            for (int i = 0; i < 8; i++) {
                float4 v4 = vj[i];
                acc[4 * i + 0] += p * v4.x; acc[4 * i + 1] += p * v4.y;
                acc[4 * i + 2] += p * v4.z; acc[4 * i + 3] += p * v4.w;
            }
        }
    }
    float inv = 1.f / l;
    int bu = bh >> 3, h = bh & 7;
    float* dst = ob + ((size_t)(bu * A_LEN + tid)) * EMB + h * HD;
#pragma unroll
    for (int i = 0; i < 8; i++) {
        float4 o4;
        o4.x = acc[4 * i + 0] * inv; o4.y = acc[4 * i + 1] * inv;
        o4.z = acc[4 * i + 2] * inv; o4.w = acc[4 * i + 3] * inv;
        ((float4*)dst)[i] = o4;
    }
}

// ---------------------------------------------------------------------------
// Kernel 4: out-proj + residual: out = z + attn @ Wo^T + ff_b
// ---------------------------------------------------------------------------
__global__ __launch_bounds__(256) void oproj_kernel(const float* __restrict__ attn,
                                                    const float* __restrict__ Wo,
                                                    const float* __restrict__ obias,
                                                    const float* __restrict__ z,
                                                    float* __restrict__ out) {
    __shared__ float xs[TPB][EMB];   // 16 KB
    int tid = threadIdx.x;
    int t0 = blockIdx.x * TPB;
    const float4* src = (const float4*)(attn + (size_t)t0 * EMB);
    float4* d4 = (float4*)xs;
    for (int i = tid; i < 1024; i += 256) d4[i] = src[i];
    __syncthreads();

    float acc[TPB];
#pragma unroll
    for (int t = 0; t < TPB; t++) acc[t] = 0.f;
    for (int k = 0; k < EMB; k += 16) {
        const float4* wp = (const float4*)(Wo + (size_t)tid * EMB + k);
        float4 w0 = wp[0], w1 = wp[1], w2 = wp[2], w3 = wp[3];
#pragma unroll
        for (int tok = 0; tok < TPB; tok++) {
            const float4* xp = (const float4*)&xs[tok][k];
            acc[tok] += dot4(w0, xp[0]) + dot4(w1, xp[1]) +
                        dot4(w2, xp[2]) + dot4(w3, xp[3]);
        }
    }
    float bias = obias[tid];
#pragma unroll
    for (int tok = 0; tok < TPB; tok++) {
        size_t off = (size_t)(t0 + tok) * EMB + tid;
        out[off] = z[off] + acc[tok] + bias;
    }
}

// ---------------------------------------------------------------------------
// Kernel 5: FFN in place on out: out = z1 + W2@gelu(W1@LN2(z1)+b1)+b2
// ---------------------------------------------------------------------------
__global__ __launch_bounds__(256) void ffn_kernel(const float* __restrict__ ln_g,
                                                  const float* __restrict__ ln_b,
                                                  const float* __restrict__ W1,
                                                  const float* __restrict__ b1,
                                                  const float* __restrict__ W2,
                                                  const float* __restrict__ b2,
                                                  float* __restrict__ out) {
    __shared__ float z1[TPB][EMB];   // 16 KB
    __shared__ float xn[TPB][EMB];   // 16 KB
    __shared__ float hb[TPB][EMB];   // 16 KB
    int tid = threadIdx.x;
    int t0 = blockIdx.x * TPB;
    const float4* src = (const float4*)(out + (size_t)t0 * EMB);
    float4* z4 = (float4*)z1;
    for (int i = tid; i < 1024; i += 256) z4[i] = src[i];
    __syncthreads();

    {   // LN2, 16 lanes per row
        int row = tid >> 4, sub = tid & 15;
        float* zr = &z1[row][sub * 16];
        float vals[16];
        float s = 0.f, ss = 0.f;
#pragma unroll
        for (int i = 0; i < 16; i++) {
            float v = zr[i];
            vals[i] = v; s += v; ss += v * v;
        }
#pragma unroll
        for (int off = 8; off >= 1; off >>= 1) {
            s += __shfl_xor(s, off);
            ss += __shfl_xor(ss, off);
        }
        float mu = s * (1.0f / EMB);
        float inv = rsqrtf(ss * (1.0f / EMB) - mu * mu + 1e-5f);
        int cb = sub * 16;
#pragma unroll
        for (int i = 0; i < 16; i++)
            xn[row][cb + i] = (vals[i] - mu) * inv * ln_g[cb + i] + ln_b[cb + i];
    }
    __syncthreads();

    float acc[TPB];
#pragma unroll
    for (int t = 0; t < TPB; t++) acc[t] = 0.f;
    for (int k = 0; k < EMB; k += 16) {
        const float4* wp = (const float4*)(W1 + (size_t)tid * EMB + k);
        float4 w0 = wp[0], w1 = wp[1], w2 = wp[2], w3 = wp[3];
#pragma unroll
        for (int tok = 0; tok < TPB; tok++) {
            const float4* xp = (const float4*)&xn[tok][k];
            acc[tok] += dot4(w0, xp[0]) + dot4(w1, xp[1]) +
                        dot4(w2, xp[2]) + dot4(w3, xp[3]);
        }
    }
    float bias1 = b1[tid];
#pragma unroll
    for (int tok = 0; tok < TPB; tok++) {
        float x = acc[tok] + bias1;
        hb[tok][tid] = 0.5f * x * (1.0f + erff(x * 0.7071067811865476f));
    }
    __syncthreads();

    float acc2[TPB];
#pragma unroll
    for (int t = 0; t < TPB; t++) acc2[t] = 0.f;
    for (int k = 0; k < EMB; k += 16) {
        const float4* wp = (const float4*)(W2 + (size_t)tid * EMB + k);
        float4 w0 = wp[0], w1 = wp[1], w2 = wp[2], w3 = wp[3];
#pragma unroll
        for (int tok = 0; tok < TPB; tok++) {
            const float4* xp = (const float4*)&hb[tok][k];
            acc2[tok] += dot4(w0, xp[0]) + dot4(w1, xp[1]) +
                         dot4(w2, xp[2]) + dot4(w3, xp[3]);
        }
    }
    float bias2 = b2[tid];
#pragma unroll
    for (int tok = 0; tok < TPB; tok++) {
        size_t off = (size_t)(t0 + tok) * EMB + tid;
        out[off] = z1[tok][tid] + acc2[tok] + bias2;
    }
}

// ---------------------------------------------------------------------------
extern "C" void kernel_launch(void* const* d_in, const int* in_sizes, int n_in,
                              void* d_out, int out_size, void* d_ws, size_t ws_size,
                              hipStream_t stream) {
    const float* z      = (const float*)d_in[0];
    const float* ln1_g  = (const float*)d_in[1];
    const float* ln1_b  = (const float*)d_in[2];
    const float* proj_v = (const float*)d_in[3];
    const float* proj_g = (const float*)d_in[4];
    const float* proj_b = (const float*)d_in[5];
    const float* ff_v   = (const float*)d_in[6];
    const float* ff_g   = (const float*)d_in[7];
    const float* ff_b   = (const float*)d_in[8];
    const float* ln2_g  = (const float*)d_in[9];
    const float* ln2_b  = (const float*)d_in[10];
    const float* w1_v   = (const float*)d_in[11];
    const float* w1_g   = (const float*)d_in[12];
    const float* w1_b   = (const float*)d_in[13];
    const float* w2_v   = (const float*)d_in[14];
    const float* w2_g   = (const float*)d_in[15];
    const float* w2_b   = (const float*)d_in[16];
    float* out = (float*)d_out;

    float* ws = (float*)d_ws;
    float* Wqkv = ws; ws += 768 * 256;
    float* Wo   = ws; ws += 256 * 256;
    float* W1   = ws; ws += 256 * 256;
    float* W2   = ws; ws += 256 * 256;
    float* qbuf = ws; ws += (size_t)TOK * EMB;
    float* kbuf = ws; ws += (size_t)TOK * EMB;
    float* vbuf = ws; ws += (size_t)TOK * EMB;
    float* abuf = ws; ws += (size_t)TOK * EMB;

    wnorm_kernel<<<768, 64, 0, stream>>>(proj_v, proj_g, Wqkv);
    wnorm_kernel<<<256, 64, 0, stream>>>(ff_v, ff_g, Wo);
    wnorm_kernel<<<256, 64, 0, stream>>>(w1_v, w1_g, W1);
    wnorm_kernel<<<256, 64, 0, stream>>>(w2_v, w2_g, W2);

    ln_qkv_rope_kernel<<<TOK / TPB, 256, 0, stream>>>(z, ln1_g, ln1_b, Wqkv,
                                                      proj_b, qbuf, kbuf, vbuf);
    attn_kernel<<<BU_N * NHEAD, 512, 0, stream>>>(qbuf, kbuf, vbuf, abuf);
    oproj_kernel<<<TOK / TPB, 256, 0, stream>>>(abuf, Wo, ff_b, z, out);
    ffn_kernel<<<TOK / TPB, 256, 0, stream>>>(ln2_g, ln2_b, W1, w1_b, W2, w2_b, out);
}

// Round 2
// 357.590 us; speedup vs baseline: 2.9623x; 2.9623x over previous
//
#include <hip/hip_runtime.h>
#include <cmath>

#define EMB 256
#define NHEAD 8
#define HD 32
#define A_LEN 512
#define TOK 32768

typedef __bf16 bf16_t;
typedef __bf16 bf16x8 __attribute__((ext_vector_type(8)));
typedef __bf16 bf16x4 __attribute__((ext_vector_type(4)));
typedef float floatx4 __attribute__((ext_vector_type(4)));

#define MFMA16(a, b, c) __builtin_amdgcn_mfma_f32_16x16x32_bf16((a), (b), (c), 0, 0, 0)

// ---------------------------------------------------------------------------
// Setup: weight_norm all 4 weights -> bf16 rows in Wall, plus RoPE cos/sin
// tables. Blocks 0..1535: one wave per weight row. Blocks 1536..1663: table.
// ---------------------------------------------------------------------------
__global__ __launch_bounds__(64) void setup_kernel(
    const float* __restrict__ proj_v, const float* __restrict__ proj_g,
    const float* __restrict__ ff_v, const float* __restrict__ ff_g,
    const float* __restrict__ w1_v, const float* __restrict__ w1_g,
    const float* __restrict__ w2_v, const float* __restrict__ w2_g,
    bf16_t* __restrict__ Wall, float* __restrict__ ctab,
    float* __restrict__ stab) {
    int b = blockIdx.x;
    int lane = threadIdx.x;
    if (b < 1536) {
        const float* v; const float* g; int r;
        if (b < 768)       { v = proj_v; g = proj_g; r = b; }
        else if (b < 1024) { v = ff_v;   g = ff_g;   r = b - 768; }
        else if (b < 1280) { v = w1_v;   g = w1_g;   r = b - 1024; }
        else               { v = w2_v;   g = w2_g;   r = b - 1280; }
        const floatx4* vr = (const floatx4*)(v + (size_t)r * 256);
        floatx4 x = vr[lane];
        float ss = x[0] * x[0] + x[1] * x[1] + x[2] * x[2] + x[3] * x[3];
#pragma unroll
        for (int off = 32; off >= 1; off >>= 1) ss += __shfl_xor(ss, off);
        float sc = g[r] * rsqrtf(ss);
        bf16x4 o;
        o[0] = (bf16_t)(x[0] * sc); o[1] = (bf16_t)(x[1] * sc);
        o[2] = (bf16_t)(x[2] * sc); o[3] = (bf16_t)(x[3] * sc);
        ((bf16x4*)(Wall + (size_t)b * 256))[lane] = o;
    } else {
        int idx = (b - 1536) * 64 + lane;     // 0..8191 = a*16 + i
        int a = idx >> 4, i = idx & 15;
        float freq = expf(-(float)(2 * i) * 0.2878231366242558f); // ln(1e4)/32
        float ang = (float)a * freq;
        ctab[idx] = cosf(ang);
        stab[idx] = sinf(ang);
    }
}

// ---------------------------------------------------------------------------
// QKV: LN1 -> bf16 xn (LDS) -> MFMA GEMM vs Wqkv[768][256] -> bias -> RoPE ->
// scatter q (pre-scaled by 1/sqrt(32)), k, v as bf16 in [bu,h,a,d] layout.
// Block: 256 thr = 4 waves, 64 tokens. Wave w owns output cols [w*192,(w+1)*192).
// ---------------------------------------------------------------------------
__global__ __launch_bounds__(256, 2) void qkv_kernel(
    const float* __restrict__ z, const float* __restrict__ ln_g,
    const float* __restrict__ ln_b, const bf16_t* __restrict__ W,
    const float* __restrict__ pb, const float* __restrict__ ctab,
    const float* __restrict__ stab, bf16_t* __restrict__ qbf,
    bf16_t* __restrict__ kbf, bf16_t* __restrict__ vbf) {
    __shared__ bf16_t xns[64 * 264];   // row stride 264 (+8 pad: 2-way banks)
    int tid = threadIdx.x;
    int t0 = blockIdx.x * 64;

    // ---- LN1 over 64 tokens, 16 lanes per token, 4 passes ----
#pragma unroll
    for (int it = 0; it < 4; ++it) {
        int row = it * 16 + (tid >> 4);
        int sub = tid & 15;
        const floatx4* zr = (const floatx4*)(z + (size_t)(t0 + row) * 256 + sub * 16);
        floatx4 v0 = zr[0], v1 = zr[1], v2 = zr[2], v3 = zr[3];
        float vals[16];
        ((floatx4*)vals)[0] = v0; ((floatx4*)vals)[1] = v1;
        ((floatx4*)vals)[2] = v2; ((floatx4*)vals)[3] = v3;
        float s = 0.f, q2 = 0.f;
#pragma unroll
        for (int i = 0; i < 16; ++i) { s += vals[i]; q2 += vals[i] * vals[i]; }
#pragma unroll
        for (int off = 8; off >= 1; off >>= 1) {
            s += __shfl_xor(s, off);
            q2 += __shfl_xor(q2, off);
        }
        float mu = s * (1.f / 256.f);
        float inv = rsqrtf(q2 * (1.f / 256.f) - mu * mu + 1e-5f);
        int cb = sub * 16;
        bf16x8 o0, o1;
#pragma unroll
        for (int i = 0; i < 8; ++i)
            o0[i] = (bf16_t)((vals[i] - mu) * inv * ln_g[cb + i] + ln_b[cb + i]);
#pragma unroll
        for (int i = 0; i < 8; ++i)
            o1[i] = (bf16_t)((vals[8 + i] - mu) * inv * ln_g[cb + 8 + i] + ln_b[cb + 8 + i]);
        *(bf16x8*)&xns[row * 264 + cb] = o0;
        *(bf16x8*)&xns[row * 264 + cb + 8] = o1;
    }
    __syncthreads();

    int wv = tid >> 6, lane = tid & 63, quad = lane >> 4, lidx = lane & 15;

    bf16x8 afr[4][8];
#pragma unroll
    for (int mt = 0; mt < 4; ++mt)
#pragma unroll
        for (int kc = 0; kc < 8; ++kc)
            afr[mt][kc] = *(const bf16x8*)&xns[(mt * 16 + lidx) * 264 + kc * 32 + quad * 8];

#pragma unroll 1
    for (int nt = 0; nt < 12; ++nt) {
        int nbase = wv * 192 + nt * 16;
        int n = nbase + lidx;
        bf16x8 bfr[8];
#pragma unroll
        for (int kc = 0; kc < 8; ++kc)
            bfr[kc] = *(const bf16x8*)&W[(size_t)n * 256 + kc * 32 + quad * 8];
        floatx4 acc[4];
#pragma unroll
        for (int mt = 0; mt < 4; ++mt) acc[mt] = (floatx4){0.f, 0.f, 0.f, 0.f};
#pragma unroll
        for (int kc = 0; kc < 8; ++kc)
#pragma unroll
            for (int mt = 0; mt < 4; ++mt)
                acc[mt] = MFMA16(afr[mt][kc], bfr[kc], acc[mt]);

        // epilogue: bias + rope + scatter. Tile-uniform classification:
        float bias = pb[n];
        int htile = nbase / 96;
        int rem = nbase % 96;
        int sec = rem >> 5;               // 0=q 1=k 2=v (16-tiles never straddle)
        int d = (rem & 31) + lidx;        // dim within head
#pragma unroll
        for (int mt = 0; mt < 4; ++mt) {
#pragma unroll
            for (int r = 0; r < 4; ++r) {
                int tok = t0 + mt * 16 + quad * 4 + r;
                int a = tok & 511;
                int bu = tok >> 9;
                float val = acc[mt][r] + bias;
                size_t addr = ((size_t)((bu * 8 + htile) * 512 + a)) * 32 + d;
                if (sec == 2) {
                    vbf[addr] = (bf16_t)val;
                } else {
                    float part = __shfl_xor(val, 1);   // rope partner (d^1)
                    float cs = ctab[a * 16 + (d >> 1)];
                    float sn = stab[a * 16 + (d >> 1)];
                    float res = ((d & 1) == 0) ? (val * cs - part * sn)
                                               : (val * cs + part * sn);
                    if (sec == 0)
                        qbf[addr] = (bf16_t)(res * 0.17677669529663687f);
                    else
                        kbf[addr] = (bf16_t)res;
                }
            }
        }
    }
}

// ---------------------------------------------------------------------------
// Attention: block = 4 waves x 16 queries for one (bu,h). Flash online
// softmax over key chunks of 64. K chunk LDS [64][40] bf16; V transposed to
// LDS [32][72] bf16; P round-trips through wave-private LDS [16][68] fp32.
// Writes attention output as bf16 to abuf[tok][256] at cols h*32..h*32+31.
// ---------------------------------------------------------------------------
__global__ __launch_bounds__(256) void attn_kernel(
    const bf16_t* __restrict__ qbf, const bf16_t* __restrict__ kbf,
    const bf16_t* __restrict__ vbf, bf16_t* __restrict__ ob) {
    __shared__ bf16_t Kls[64 * 40];
    __shared__ bf16_t Vt[32 * 72];
    __shared__ float Pls[4 * 16 * 68];
    int tid = threadIdx.x;
    int wv = tid >> 6, lane = tid & 63, quad = lane >> 4, lidx = lane & 15;
    int bu = blockIdx.x >> 6;
    int rem = blockIdx.x & 63;
    int h = rem >> 3, qc = rem & 7;
    size_t hb = (size_t)(bu * 8 + h) * (A_LEN * HD);
    int qbase = qc * 64 + wv * 16;

    bf16x8 qfrag = *(const bf16x8*)&qbf[hb + (size_t)(qbase + lidx) * 32 + quad * 8];

    float m_[4], l_[4];
    floatx4 Oacc[2];
#pragma unroll
    for (int r = 0; r < 4; ++r) { m_[r] = -1e30f; l_[r] = 0.f; }
    Oacc[0] = (floatx4){0.f, 0.f, 0.f, 0.f};
    Oacc[1] = (floatx4){0.f, 0.f, 0.f, 0.f};

    const floatx4 zero4 = (floatx4){0.f, 0.f, 0.f, 0.f};

    for (int kc = 0; kc < 8; ++kc) {
        __syncthreads();
        {   // stage K chunk + V^T chunk
            int row = tid >> 2;               // key within chunk 0..63
            int db = (tid & 3) * 8;           // dim base
            bf16x8 kv = *(const bf16x8*)&kbf[hb + (size_t)(kc * 64 + row) * 32 + db];
            *(bf16x8*)&Kls[row * 40 + db] = kv;
            bf16x8 vv = *(const bf16x8*)&vbf[hb + (size_t)(kc * 64 + row) * 32 + db];
#pragma unroll
            for (int j = 0; j < 8; ++j) Vt[(db + j) * 72 + row] = vv[j];
        }
        __syncthreads();

        floatx4 sc[4];
#pragma unroll
        for (int t = 0; t < 4; ++t) {
            bf16x8 kf = *(const bf16x8*)&Kls[(t * 16 + lidx) * 40 + quad * 8];
            sc[t] = MFMA16(qfrag, kf, zero4);
        }
        // online softmax update (rows = quad*4+r, cols across 16 lanes)
#pragma unroll
        for (int r = 0; r < 4; ++r) {
            float tm = fmaxf(fmaxf(sc[0][r], sc[1][r]), fmaxf(sc[2][r], sc[3][r]));
#pragma unroll
            for (int off = 8; off >= 1; off >>= 1) tm = fmaxf(tm, __shfl_xor(tm, off));
            float mn = fmaxf(m_[r], tm);
            float alpha = __expf(m_[r] - mn);
            m_[r] = mn;
            l_[r] *= alpha;
            Oacc[0][r] *= alpha;
            Oacc[1][r] *= alpha;
            float ps = 0.f;
#pragma unroll
            for (int t = 0; t < 4; ++t) {
                float p = __expf(sc[t][r] - mn);
                ps += p;
                Pls[wv * 1088 + (quad * 4 + r) * 68 + t * 16 + lidx] = p;
            }
#pragma unroll
            for (int off = 8; off >= 1; off >>= 1) ps += __shfl_xor(ps, off);
            l_[r] += ps;
        }
        // PV: O += P(16x64) * V(64x32)
#pragma unroll
        for (int ks = 0; ks < 2; ++ks) {
            const float* pr = &Pls[wv * 1088 + lidx * 68 + ks * 32 + quad * 8];
            bf16x8 pf;
#pragma unroll
            for (int j = 0; j < 8; ++j) pf[j] = (bf16_t)pr[j];
#pragma unroll
            for (int nt = 0; nt < 2; ++nt) {
                bf16x8 vf = *(const bf16x8*)&Vt[(nt * 16 + lidx) * 72 + ks * 32 + quad * 8];
                Oacc[nt] = MFMA16(pf, vf, Oacc[nt]);
            }
        }
    }
#pragma unroll
    for (int nt = 0; nt < 2; ++nt)
#pragma unroll
        for (int r = 0; r < 4; ++r) {
            int tok = bu * 512 + qbase + quad * 4 + r;
            ob[(size_t)tok * 256 + h * 32 + nt * 16 + lidx] =
                (bf16_t)(Oacc[nt][r] / l_[r]);
        }
}

// ---------------------------------------------------------------------------
// O-proj + residual: out = z + X(bf16) @ Wo^T + ff_b. 64 tokens/block.
// ---------------------------------------------------------------------------
__global__ __launch_bounds__(256, 2) void oproj_kernel(
    const bf16_t* __restrict__ X, const bf16_t* __restrict__ W,
    const float* __restrict__ bias_, const float* __restrict__ zin,
    float* __restrict__ outp) {
    int tid = threadIdx.x;
    int t0 = blockIdx.x * 64;
    int wv = tid >> 6, lane = tid & 63, quad = lane >> 4, lidx = lane & 15;
    bf16x8 afr[4][8];
#pragma unroll
    for (int mt = 0; mt < 4; ++mt)
#pragma unroll
        for (int kc = 0; kc < 8; ++kc)
            afr[mt][kc] = *(const bf16x8*)&X[(size_t)(t0 + mt * 16 + lidx) * 256 + kc * 32 + quad * 8];
#pragma unroll 1
    for (int nt = 0; nt < 4; ++nt) {
        int n = wv * 64 + nt * 16 + lidx;
        bf16x8 bfr[8];
#pragma unroll
        for (int kc = 0; kc < 8; ++kc)
            bfr[kc] = *(const bf16x8*)&W[(size_t)n * 256 + kc * 32 + quad * 8];
        floatx4 acc[4];
#pragma unroll
        for (int mt = 0; mt < 4; ++mt) acc[mt] = (floatx4){0.f, 0.f, 0.f, 0.f};
#pragma unroll
        for (int kc = 0; kc < 8; ++kc)
#pragma unroll
            for (int mt = 0; mt < 4; ++mt)
                acc[mt] = MFMA16(afr[mt][kc], bfr[kc], acc[mt]);
        float b = bias_[n];
#pragma unroll
        for (int mt = 0; mt < 4; ++mt)
#pragma unroll
            for (int r = 0; r < 4; ++r) {
                size_t o = (size_t)(t0 + mt * 16 + quad * 4 + r) * 256 + n;
                outp[o] = zin[o] + acc[mt][r] + b;
            }
    }
}

// ---------------------------------------------------------------------------
// FFN part 1: LN2(out) -> GEMM W1 -> +b1 -> exact GELU -> hbuf (bf16)
// ---------------------------------------------------------------------------
__global__ __launch_bounds__(256, 2) void ffn1_kernel(
    const float* __restrict__ outp, const float* __restrict__ ln_g,
    const float* __restrict__ ln_b, const bf16_t* __restrict__ W,
    const float* __restrict__ b1, bf16_t* __restrict__ hbuf) {
    __shared__ bf16_t xns[64 * 264];
    int tid = threadIdx.x;
    int t0 = blockIdx.x * 64;
#pragma unroll
    for (int it = 0; it < 4; ++it) {
        int row = it * 16 + (tid >> 4);
        int sub = tid & 15;
        const floatx4* zr = (const floatx4*)(outp + (size_t)(t0 + row) * 256 + sub * 16);
        floatx4 v0 = zr[0], v1 = zr[1], v2 = zr[2], v3 = zr[3];
        float vals[16];
        ((floatx4*)vals)[0] = v0; ((floatx4*)vals)[1] = v1;
        ((floatx4*)vals)[2] = v2; ((floatx4*)vals)[3] = v3;
        float s = 0.f, q2 = 0.f;
#pragma unroll
        for (int i = 0; i < 16; ++i) { s += vals[i]; q2 += vals[i] * vals[i]; }
#pragma unroll
        for (int off = 8; off >= 1; off >>= 1) {
            s += __shfl_xor(s, off);
            q2 += __shfl_xor(q2, off);
        }
        float mu = s * (1.f / 256.f);
        float inv = rsqrtf(q2 * (1.f / 256.f) - mu * mu + 1e-5f);
        int cb = sub * 16;
        bf16x8 o0, o1;
#pragma unroll
        for (int i = 0; i < 8; ++i)
            o0[i] = (bf16_t)((vals[i] - mu) * inv * ln_g[cb + i] + ln_b[cb + i]);
#pragma unroll
        for (int i = 0; i < 8; ++i)
            o1[i] = (bf16_t)((vals[8 + i] - mu) * inv * ln_g[cb + 8 + i] + ln_b[cb + 8 + i]);
        *(bf16x8*)&xns[row * 264 + cb] = o0;
        *(bf16x8*)&xns[row * 264 + cb + 8] = o1;
    }
    __syncthreads();
    int wv = tid >> 6, lane = tid & 63, quad = lane >> 4, lidx = lane & 15;
    bf16x8 afr[4][8];
#pragma unroll
    for (int mt = 0; mt < 4; ++mt)
#pragma unroll
        for (int kc = 0; kc < 8; ++kc)
            afr[mt][kc] = *(const bf16x8*)&xns[(mt * 16 + lidx) * 264 + kc * 32 + quad * 8];
#pragma unroll 1
    for (int nt = 0; nt < 4; ++nt) {
        int n = wv * 64 + nt * 16 + lidx;
        bf16x8 bfr[8];
#pragma unroll
        for (int kc = 0; kc < 8; ++kc)
            bfr[kc] = *(const bf16x8*)&W[(size_t)n * 256 + kc * 32 + quad * 8];
        floatx4 acc[4];
#pragma unroll
        for (int mt = 0; mt < 4; ++mt) acc[mt] = (floatx4){0.f, 0.f, 0.f, 0.f};
#pragma unroll
        for (int kc = 0; kc < 8; ++kc)
#pragma unroll
            for (int mt = 0; mt < 4; ++mt)
                acc[mt] = MFMA16(afr[mt][kc], bfr[kc], acc[mt]);
        float b = b1[n];
#pragma unroll
        for (int mt = 0; mt < 4; ++mt)
#pragma unroll
            for (int r = 0; r < 4; ++r) {
                float x = acc[mt][r] + b;
                float gel = 0.5f * x * (1.f + erff(x * 0.7071067811865476f));
                hbuf[(size_t)(t0 + mt * 16 + quad * 4 + r) * 256 + n] = (bf16_t)gel;
            }
    }
}

// ---------------------------------------------------------------------------
// FFN part 2: out += hbuf @ W2^T + b2   (in-place residual on d_out)
// ---------------------------------------------------------------------------
__global__ __launch_bounds__(256, 2) void ffn2_kernel(
    const bf16_t* __restrict__ X, const bf16_t* __restrict__ W,
    const float* __restrict__ b2, float* __restrict__ outp) {
    int tid = threadIdx.x;
    int t0 = blockIdx.x * 64;
    int wv = tid >> 6, lane = tid & 63, quad = lane >> 4, lidx = lane & 15;
    bf16x8 afr[4][8];
#pragma unroll
    for (int mt = 0; mt < 4; ++mt)
#pragma unroll
        for (int kc = 0; kc < 8; ++kc)
            afr[mt][kc] = *(const bf16x8*)&X[(size_t)(t0 + mt * 16 + lidx) * 256 + kc * 32 + quad * 8];
#pragma unroll 1
    for (int nt = 0; nt < 4; ++nt) {
        int n = wv * 64 + nt * 16 + lidx;
        bf16x8 bfr[8];
#pragma unroll
        for (int kc = 0; kc < 8; ++kc)
            bfr[kc] = *(const bf16x8*)&W[(size_t)n * 256 + kc * 32 + quad * 8];
        floatx4 acc[4];
#pragma unroll
        for (int mt = 0; mt < 4; ++mt) acc[mt] = (floatx4){0.f, 0.f, 0.f, 0.f};
#pragma unroll
        for (int kc = 0; kc < 8; ++kc)
#pragma unroll
            for (int mt = 0; mt < 4; ++mt)
                acc[mt] = MFMA16(afr[mt][kc], bfr[kc], acc[mt]);
        float b = b2[n];
#pragma unroll
        for (int mt = 0; mt < 4; ++mt)
#pragma unroll
            for (int r = 0; r < 4; ++r) {
                size_t o = (size_t)(t0 + mt * 16 + quad * 4 + r) * 256 + n;
                outp[o] = outp[o] + acc[mt][r] + b;
            }
    }
}

// ---------------------------------------------------------------------------
extern "C" void kernel_launch(void* const* d_in, const int* in_sizes, int n_in,
                              void* d_out, int out_size, void* d_ws, size_t ws_size,
                              hipStream_t stream) {
    const float* z      = (const float*)d_in[0];
    const float* ln1_g  = (const float*)d_in[1];
    const float* ln1_b  = (const float*)d_in[2];
    const float* proj_v = (const float*)d_in[3];
    const float* proj_g = (const float*)d_in[4];
    const float* proj_b = (const float*)d_in[5];
    const float* ff_v   = (const float*)d_in[6];
    const float* ff_g   = (const float*)d_in[7];
    const float* ff_b   = (const float*)d_in[8];
    const float* ln2_g  = (const float*)d_in[9];
    const float* ln2_b  = (const float*)d_in[10];
    const float* w1_v   = (const float*)d_in[11];
    const float* w1_g   = (const float*)d_in[12];
    const float* w1_b   = (const float*)d_in[13];
    const float* w2_v   = (const float*)d_in[14];
    const float* w2_g   = (const float*)d_in[15];
    const float* w2_b   = (const float*)d_in[16];
    float* out = (float*)d_out;

    char* p = (char*)d_ws;
    bf16_t* Wall = (bf16_t*)p; p += (size_t)1536 * 256 * 2;
    float* ctab  = (float*)p;  p += 8192 * 4;
    float* stab  = (float*)p;  p += 8192 * 4;
    bf16_t* qbf  = (bf16_t*)p; p += (size_t)TOK * 256 * 2;
    bf16_t* kbf  = (bf16_t*)p; p += (size_t)TOK * 256 * 2;
    bf16_t* vbf  = (bf16_t*)p; p += (size_t)TOK * 256 * 2;
    bf16_t* abuf = (bf16_t*)p; p += (size_t)TOK * 256 * 2;
    bf16_t* hbuf = (bf16_t*)p; p += (size_t)TOK * 256 * 2;

    const bf16_t* Wqkv = Wall;
    const bf16_t* Wo   = Wall + (size_t)768 * 256;
    const bf16_t* W1   = Wall + (size_t)1024 * 256;
    const bf16_t* W2   = Wall + (size_t)1280 * 256;

    setup_kernel<<<1664, 64, 0, stream>>>(proj_v, proj_g, ff_v, ff_g,
                                          w1_v, w1_g, w2_v, w2_g,
                                          Wall, ctab, stab);
    qkv_kernel<<<TOK / 64, 256, 0, stream>>>(z, ln1_g, ln1_b, Wqkv, proj_b,
                                             ctab, stab, qbf, kbf, vbf);
    attn_kernel<<<64 * 8 * 8, 256, 0, stream>>>(qbf, kbf, vbf, abuf);
    oproj_kernel<<<TOK / 64, 256, 0, stream>>>(abuf, Wo, ff_b, z, out);
    ffn1_kernel<<<TOK / 64, 256, 0, stream>>>(out, ln2_g, ln2_b, W1, w1_b, hbuf);
    ffn2_kernel<<<TOK / 64, 256, 0, stream>>>(hbuf, W2, w2_b, out);
}

// Round 4
// 323.194 us; speedup vs baseline: 3.2776x; 1.1064x over previous
//
#include <hip/hip_runtime.h>
#include <cmath>

#define EMB 256
#define NHEAD 8
#define HD 32
#define A_LEN 512
#define TOK 32768

typedef __bf16 bf16_t;
typedef __bf16 bf16x8 __attribute__((ext_vector_type(8)));
typedef __bf16 bf16x4 __attribute__((ext_vector_type(4)));
typedef float floatx4 __attribute__((ext_vector_type(4)));

#define MFMA16(a, b, c) __builtin_amdgcn_mfma_f32_16x16x32_bf16((a), (b), (c), 0, 0, 0)

// K LDS row stride (bf16): 36 -> word stride 18, 16 distinct bank phases.
#define KST 36
// V^T LDS row stride (bf16): 514 -> word stride 257 === 1 mod 32.
#define VST 514
// P LDS row stride (bf16)
#define PST 72

// ---------------------------------------------------------------------------
// Setup: weight_norm all 4 weights -> bf16 rows in Wall, plus RoPE cos/sin
// tables. Blocks 0..1535: one wave per weight row. Blocks 1536..1663: table.
// ---------------------------------------------------------------------------
__global__ __launch_bounds__(64) void setup_kernel(
    const float* __restrict__ proj_v, const float* __restrict__ proj_g,
    const float* __restrict__ ff_v, const float* __restrict__ ff_g,
    const float* __restrict__ w1_v, const float* __restrict__ w1_g,
    const float* __restrict__ w2_v, const float* __restrict__ w2_g,
    bf16_t* __restrict__ Wall, float* __restrict__ ctab,
    float* __restrict__ stab) {
    int b = blockIdx.x;
    int lane = threadIdx.x;
    if (b < 1536) {
        const float* v; const float* g; int r;
        if (b < 768)       { v = proj_v; g = proj_g; r = b; }
        else if (b < 1024) { v = ff_v;   g = ff_g;   r = b - 768; }
        else if (b < 1280) { v = w1_v;   g = w1_g;   r = b - 1024; }
        else               { v = w2_v;   g = w2_g;   r = b - 1280; }
        const floatx4* vr = (const floatx4*)(v + (size_t)r * 256);
        floatx4 x = vr[lane];
        float ss = x[0] * x[0] + x[1] * x[1] + x[2] * x[2] + x[3] * x[3];
#pragma unroll
        for (int off = 32; off >= 1; off >>= 1) ss += __shfl_xor(ss, off);
        float sc = g[r] * rsqrtf(ss);
        bf16x4 o;
        o[0] = (bf16_t)(x[0] * sc); o[1] = (bf16_t)(x[1] * sc);
        o[2] = (bf16_t)(x[2] * sc); o[3] = (bf16_t)(x[3] * sc);
        ((bf16x4*)(Wall + (size_t)b * 256))[lane] = o;
    } else {
        int idx = (b - 1536) * 64 + lane;     // 0..8191 = a*16 + i
        int a = idx >> 4, i = idx & 15;
        float freq = expf(-(float)(2 * i) * 0.2878231366242558f); // ln(1e4)/32
        float ang = (float)a * freq;
        ctab[idx] = cosf(ang);
        stab[idx] = sinf(ang);
    }
}

// ---------------------------------------------------------------------------
// QKV: LN1 -> bf16 xn (LDS) -> MFMA GEMM vs Wqkv[768][256] -> bias -> RoPE ->
// scatter q (pre-scaled by 1/sqrt(32)), k, v as bf16 in [bu,h,a,d] layout.
// ---------------------------------------------------------------------------
__global__ __launch_bounds__(256, 2) void qkv_kernel(
    const float* __restrict__ z, const float* __restrict__ ln_g,
    const float* __restrict__ ln_b, const bf16_t* __restrict__ W,
    const float* __restrict__ pb, const float* __restrict__ ctab,
    const float* __restrict__ stab, bf16_t* __restrict__ qbf,
    bf16_t* __restrict__ kbf, bf16_t* __restrict__ vbf) {
    __shared__ bf16_t xns[64 * 264];
    int tid = threadIdx.x;
    int t0 = blockIdx.x * 64;

#pragma unroll
    for (int it = 0; it < 4; ++it) {
        int row = it * 16 + (tid >> 4);
        int sub = tid & 15;
        const floatx4* zr = (const floatx4*)(z + (size_t)(t0 + row) * 256 + sub * 16);
        floatx4 v0 = zr[0], v1 = zr[1], v2 = zr[2], v3 = zr[3];
        float vals[16];
        ((floatx4*)vals)[0] = v0; ((floatx4*)vals)[1] = v1;
        ((floatx4*)vals)[2] = v2; ((floatx4*)vals)[3] = v3;
        float s = 0.f, q2 = 0.f;
#pragma unroll
        for (int i = 0; i < 16; ++i) { s += vals[i]; q2 += vals[i] * vals[i]; }
#pragma unroll
        for (int off = 8; off >= 1; off >>= 1) {
            s += __shfl_xor(s, off);
            q2 += __shfl_xor(q2, off);
        }
        float mu = s * (1.f / 256.f);
        float inv = rsqrtf(q2 * (1.f / 256.f) - mu * mu + 1e-5f);
        int cb = sub * 16;
        bf16x8 o0, o1;
#pragma unroll
        for (int i = 0; i < 8; ++i)
            o0[i] = (bf16_t)((vals[i] - mu) * inv * ln_g[cb + i] + ln_b[cb + i]);
#pragma unroll
        for (int i = 0; i < 8; ++i)
            o1[i] = (bf16_t)((vals[8 + i] - mu) * inv * ln_g[cb + 8 + i] + ln_b[cb + 8 + i]);
        *(bf16x8*)&xns[row * 264 + cb] = o0;
        *(bf16x8*)&xns[row * 264 + cb + 8] = o1;
    }
    __syncthreads();

    int wv = tid >> 6, lane = tid & 63, quad = lane >> 4, lidx = lane & 15;

    bf16x8 afr[4][8];
#pragma unroll
    for (int mt = 0; mt < 4; ++mt)
#pragma unroll
        for (int kc = 0; kc < 8; ++kc)
            afr[mt][kc] = *(const bf16x8*)&xns[(mt * 16 + lidx) * 264 + kc * 32 + quad * 8];

#pragma unroll 1
    for (int nt = 0; nt < 12; ++nt) {
        int nbase = wv * 192 + nt * 16;
        int n = nbase + lidx;
        bf16x8 bfr[8];
#pragma unroll
        for (int kc = 0; kc < 8; ++kc)
            bfr[kc] = *(const bf16x8*)&W[(size_t)n * 256 + kc * 32 + quad * 8];
        floatx4 acc[4];
#pragma unroll
        for (int mt = 0; mt < 4; ++mt) acc[mt] = (floatx4){0.f, 0.f, 0.f, 0.f};
#pragma unroll
        for (int kc = 0; kc < 8; ++kc)
#pragma unroll
            for (int mt = 0; mt < 4; ++mt)
                acc[mt] = MFMA16(afr[mt][kc], bfr[kc], acc[mt]);

        float bias = pb[n];
        int htile = nbase / 96;
        int rem = nbase % 96;
        int sec = rem >> 5;               // 0=q 1=k 2=v
        int d = (rem & 31) + lidx;
#pragma unroll
        for (int mt = 0; mt < 4; ++mt) {
#pragma unroll
            for (int r = 0; r < 4; ++r) {
                int tok = t0 + mt * 16 + quad * 4 + r;
                int a = tok & 511;
                int bu = tok >> 9;
                float val = acc[mt][r] + bias;
                size_t addr = ((size_t)((bu * 8 + htile) * 512 + a)) * 32 + d;
                if (sec == 2) {
                    vbf[addr] = (bf16_t)val;
                } else {
                    float part = __shfl_xor(val, 1);
                    float cs = ctab[a * 16 + (d >> 1)];
                    float sn = stab[a * 16 + (d >> 1)];
                    float res = ((d & 1) == 0) ? (val * cs - part * sn)
                                               : (val * cs + part * sn);
                    if (sec == 0)
                        qbf[addr] = (bf16_t)(res * 0.17677669529663687f);
                    else
                        kbf[addr] = (bf16_t)res;
                }
            }
        }
    }
}

// ---------------------------------------------------------------------------
// Attention: one block (512 thr = 8 waves) per (bu,h). K and V^T staged in
// LDS ONCE; each wave owns 64 queries, flash online softmax over 8 chunks of
// 64 keys with zero in-loop barriers. P round-trips as bf16 (wave-private).
// ---------------------------------------------------------------------------
__global__ __launch_bounds__(512) void attn_kernel(
    const bf16_t* __restrict__ qbf, const bf16_t* __restrict__ kbf,
    const bf16_t* __restrict__ vbf, bf16_t* __restrict__ ob) {
    __shared__ bf16_t Kls[512 * KST];     // 36.9 KB
    __shared__ bf16_t Vt[32 * VST];       // 32.9 KB
    __shared__ bf16_t Pls[8 * 16 * PST];  // 18.4 KB
    int tid = threadIdx.x;
    int wv = tid >> 6, lane = tid & 63, quad = lane >> 4, lidx = lane & 15;
    int bh = blockIdx.x;
    int bu = bh >> 3, h = bh & 7;
    size_t hb = (size_t)bh * (A_LEN * HD);

    // ---- stage K [key][d] and V^T [d][key], coalesced global reads ----
#pragma unroll
    for (int i = 0; i < 4; ++i) {
        int c = tid + i * 512;            // 16B chunk id, 0..2047
        int key = c >> 2, db = (c & 3) * 8;
        bf16x8 kv = *(const bf16x8*)&kbf[hb + (size_t)c * 8];
        *(bf16x8*)&Kls[key * KST + db] = kv;
        bf16x8 vv = *(const bf16x8*)&vbf[hb + (size_t)c * 8];
#pragma unroll
        for (int j = 0; j < 8; ++j) Vt[(db + j) * VST + key] = vv[j];
    }
    __syncthreads();

    int pb_ = wv * 16 * PST;
    const floatx4 zero4 = (floatx4){0.f, 0.f, 0.f, 0.f};

#pragma unroll 1
    for (int mt = 0; mt < 4; ++mt) {
        int q0 = wv * 64 + mt * 16;
        bf16x8 qfrag = *(const bf16x8*)&qbf[hb + (size_t)(q0 + lidx) * 32 + quad * 8];
        float m_[4], l_[4];
        floatx4 Oacc[2];
#pragma unroll
        for (int r = 0; r < 4; ++r) { m_[r] = -1e30f; l_[r] = 0.f; }
        Oacc[0] = zero4; Oacc[1] = zero4;

#pragma unroll 1
        for (int kc = 0; kc < 8; ++kc) {
            floatx4 sc[4];
#pragma unroll
            for (int t = 0; t < 4; ++t) {
                bf16x8 kf = *(const bf16x8*)&Kls[(kc * 64 + t * 16 + lidx) * KST + quad * 8];
                sc[t] = MFMA16(qfrag, kf, zero4);
            }
#pragma unroll
            for (int r = 0; r < 4; ++r) {
                float tm = fmaxf(fmaxf(sc[0][r], sc[1][r]), fmaxf(sc[2][r], sc[3][r]));
#pragma unroll
                for (int off = 8; off >= 1; off >>= 1) tm = fmaxf(tm, __shfl_xor(tm, off));
                float mn = fmaxf(m_[r], tm);
                float alpha = __expf(m_[r] - mn);
                m_[r] = mn;
                l_[r] *= alpha;
                Oacc[0][r] *= alpha;
                Oacc[1][r] *= alpha;
                float ps = 0.f;
#pragma unroll
                for (int t = 0; t < 4; ++t) {
                    float p = __expf(sc[t][r] - mn);
                    ps += p;
                    Pls[pb_ + (quad * 4 + r) * PST + t * 16 + lidx] = (bf16_t)p;
                }
#pragma unroll
                for (int off = 8; off >= 1; off >>= 1) ps += __shfl_xor(ps, off);
                l_[r] += ps;
            }
#pragma unroll
            for (int ks = 0; ks < 2; ++ks) {
                bf16x8 pf = *(const bf16x8*)&Pls[pb_ + lidx * PST + ks * 32 + quad * 8];
#pragma unroll
                for (int nt = 0; nt < 2; ++nt) {
                    bf16x8 vf = *(const bf16x8*)&Vt[(nt * 16 + lidx) * VST + kc * 64 + ks * 32 + quad * 8];
                    Oacc[nt] = MFMA16(pf, vf, Oacc[nt]);
                }
            }
        }
#pragma unroll
        for (int nt = 0; nt < 2; ++nt)
#pragma unroll
            for (int r = 0; r < 4; ++r) {
                int tok = bu * 512 + q0 + quad * 4 + r;
                ob[(size_t)tok * 256 + h * 32 + nt * 16 + lidx] =
                    (bf16_t)(Oacc[nt][r] / l_[r]);
            }
    }
}

// ---------------------------------------------------------------------------
// Fused tail: out = r1 + FFN(LN2(r1)),  r1 = z + attn@Wo^T + ff_b.
// Block = 256 thr / 64 tokens. r1 lives in registers [nt][mt][r]; LN stats
// via shuffle + cross-wave LDS reduce; xn and h stay in LDS.
// ---------------------------------------------------------------------------
__global__ __launch_bounds__(256, 2) void tail_kernel(
    const bf16_t* __restrict__ X, const bf16_t* __restrict__ Wo,
    const float* __restrict__ obias, const float* __restrict__ zin,
    const float* __restrict__ ln_g, const float* __restrict__ ln_b,
    const bf16_t* __restrict__ W1, const float* __restrict__ b1,
    const bf16_t* __restrict__ W2, const float* __restrict__ b2,
    float* __restrict__ outp) {
    __shared__ bf16_t xns[64 * 264];   // 33.8 KB
    __shared__ bf16_t hs[64 * 264];    // 33.8 KB
    __shared__ float red[64 * 8];      // per-token per-wave partial s,ss
    __shared__ float mi[64 * 2];       // per-token mu, inv
    int tid = threadIdx.x;
    int t0 = blockIdx.x * 64;
    int wv = tid >> 6, lane = tid & 63, quad = lane >> 4, lidx = lane & 15;

    // ---- o-proj GEMM: r1 = z + X@Wo^T + ff_b (regs) ----
    bf16x8 afr[4][8];
#pragma unroll
    for (int mt = 0; mt < 4; ++mt)
#pragma unroll
        for (int kc = 0; kc < 8; ++kc)
            afr[mt][kc] = *(const bf16x8*)&X[(size_t)(t0 + mt * 16 + lidx) * 256 + kc * 32 + quad * 8];

    float r1[4][4][4];   // [nt][mt][r]
#pragma unroll 1
    for (int nt = 0; nt < 4; ++nt) {
        int n = wv * 64 + nt * 16 + lidx;
        bf16x8 bfr[8];
#pragma unroll
        for (int kc = 0; kc < 8; ++kc)
            bfr[kc] = *(const bf16x8*)&Wo[(size_t)n * 256 + kc * 32 + quad * 8];
        floatx4 acc[4];
#pragma unroll
        for (int mt = 0; mt < 4; ++mt) acc[mt] = (floatx4){0.f, 0.f, 0.f, 0.f};
#pragma unroll
        for (int kc = 0; kc < 8; ++kc)
#pragma unroll
            for (int mt = 0; mt < 4; ++mt)
                acc[mt] = MFMA16(afr[mt][kc], bfr[kc], acc[mt]);
        float b = obias[n];
#pragma unroll
        for (int mt = 0; mt < 4; ++mt)
#pragma unroll
            for (int r = 0; r < 4; ++r) {
                size_t o = (size_t)(t0 + mt * 16 + quad * 4 + r) * 256 + n;
                r1[nt][mt][r] = zin[o] + acc[mt][r] + b;
            }
    }

    // ---- LN2 stats: per-row partials -> shuffle over lidx -> LDS ----
#pragma unroll
    for (int mt = 0; mt < 4; ++mt)
#pragma unroll
        for (int r = 0; r < 4; ++r) {
            float s = 0.f, ss = 0.f;
#pragma unroll
            for (int nt = 0; nt < 4; ++nt) {
                float v = r1[nt][mt][r];
                s += v; ss += v * v;
            }
#pragma unroll
            for (int off = 8; off >= 1; off >>= 1) {
                s += __shfl_xor(s, off);
                ss += __shfl_xor(ss, off);
            }
            if (lidx == 0) {
                int row = mt * 16 + quad * 4 + r;
                red[row * 8 + wv * 2] = s;
                red[row * 8 + wv * 2 + 1] = ss;
            }
        }
    __syncthreads();
    if (tid < 64) {
        float s = 0.f, ss = 0.f;
#pragma unroll
        for (int w = 0; w < 4; ++w) {
            s += red[tid * 8 + w * 2];
            ss += red[tid * 8 + w * 2 + 1];
        }
        float mu = s * (1.f / 256.f);
        mi[tid * 2] = mu;
        mi[tid * 2 + 1] = rsqrtf(ss * (1.f / 256.f) - mu * mu + 1e-5f);
    }
    __syncthreads();

    // ---- write xn = LN2(r1) to LDS (bf16) ----
    float gv[4], bv[4];
#pragma unroll
    for (int nt = 0; nt < 4; ++nt) {
        int n = wv * 64 + nt * 16 + lidx;
        gv[nt] = ln_g[n]; bv[nt] = ln_b[n];
    }
#pragma unroll
    for (int mt = 0; mt < 4; ++mt)
#pragma unroll
        for (int r = 0; r < 4; ++r) {
            int row = mt * 16 + quad * 4 + r;
            float mu = mi[row * 2], inv = mi[row * 2 + 1];
#pragma unroll
            for (int nt = 0; nt < 4; ++nt) {
                int n = wv * 64 + nt * 16 + lidx;
                xns[row * 264 + n] = (bf16_t)((r1[nt][mt][r] - mu) * inv * gv[nt] + bv[nt]);
            }
        }
    __syncthreads();

    // ---- FFN1: h = gelu(xn@W1^T + b1) -> LDS ----
#pragma unroll
    for (int mt = 0; mt < 4; ++mt)
#pragma unroll
        for (int kc = 0; kc < 8; ++kc)
            afr[mt][kc] = *(const bf16x8*)&xns[(mt * 16 + lidx) * 264 + kc * 32 + quad * 8];
#pragma unroll 1
    for (int nt = 0; nt < 4; ++nt) {
        int n = wv * 64 + nt * 16 + lidx;
        bf16x8 bfr[8];
#pragma unroll
        for (int kc = 0; kc < 8; ++kc)
            bfr[kc] = *(const bf16x8*)&W1[(size_t)n * 256 + kc * 32 + quad * 8];
        floatx4 acc[4];
#pragma unroll
        for (int mt = 0; mt < 4; ++mt) acc[mt] = (floatx4){0.f, 0.f, 0.f, 0.f};
#pragma unroll
        for (int kc = 0; kc < 8; ++kc)
#pragma unroll
            for (int mt = 0; mt < 4; ++mt)
                acc[mt] = MFMA16(afr[mt][kc], bfr[kc], acc[mt]);
        float b = b1[n];
#pragma unroll
        for (int mt = 0; mt < 4; ++mt)
#pragma unroll
            for (int r = 0; r < 4; ++r) {
                float x = acc[mt][r] + b;
                float gel = 0.5f * x * (1.f + erff(x * 0.7071067811865476f));
                hs[(mt * 16 + quad * 4 + r) * 264 + n] = (bf16_t)gel;
            }
    }
    __syncthreads();

    // ---- FFN2: out = r1 + h@W2^T + b2 ----
#pragma unroll
    for (int mt = 0; mt < 4; ++mt)
#pragma unroll
        for (int kc = 0; kc < 8; ++kc)
            afr[mt][kc] = *(const bf16x8*)&hs[(mt * 16 + lidx) * 264 + kc * 32 + quad * 8];
#pragma unroll 1
    for (int nt = 0; nt < 4; ++nt) {
        int n = wv * 64 + nt * 16 + lidx;
        bf16x8 bfr[8];
#pragma unroll
        for (int kc = 0; kc < 8; ++kc)
            bfr[kc] = *(const bf16x8*)&W2[(size_t)n * 256 + kc * 32 + quad * 8];
        floatx4 acc[4];
#pragma unroll
        for (int mt = 0; mt < 4; ++mt) acc[mt] = (floatx4){0.f, 0.f, 0.f, 0.f};
#pragma unroll
        for (int kc = 0; kc < 8; ++kc)
#pragma unroll
            for (int mt = 0; mt < 4; ++mt)
                acc[mt] = MFMA16(afr[mt][kc], bfr[kc], acc[mt]);
        float b = b2[n];
#pragma unroll
        for (int mt = 0; mt < 4; ++mt)
#pragma unroll
            for (int r = 0; r < 4; ++r) {
                size_t o = (size_t)(t0 + mt * 16 + quad * 4 + r) * 256 + n;
                outp[o] = r1[nt][mt][r] + acc[mt][r] + b;
            }
    }
}

// ---------------------------------------------------------------------------
extern "C" void kernel_launch(void* const* d_in, const int* in_sizes, int n_in,
                              void* d_out, int out_size, void* d_ws, size_t ws_size,
                              hipStream_t stream) {
    const float* z      = (const float*)d_in[0];
    const float* ln1_g  = (const float*)d_in[1];
    const float* ln1_b  = (const float*)d_in[2];
    const float* proj_v = (const float*)d_in[3];
    const float* proj_g = (const float*)d_in[4];
    const float* proj_b = (const float*)d_in[5];
    const float* ff_v   = (const float*)d_in[6];
    const float* ff_g   = (const float*)d_in[7];
    const float* ff_b   = (const float*)d_in[8];
    const float* ln2_g  = (const float*)d_in[9];
    const float* ln2_b  = (const float*)d_in[10];
    const float* w1_v   = (const float*)d_in[11];
    const float* w1_g   = (const float*)d_in[12];
    const float* w1_b   = (const float*)d_in[13];
    const float* w2_v   = (const float*)d_in[14];
    const float* w2_g   = (const float*)d_in[15];
    const float* w2_b   = (const float*)d_in[16];
    float* out = (float*)d_out;

    char* p = (char*)d_ws;
    bf16_t* Wall = (bf16_t*)p; p += (size_t)1536 * 256 * 2;
    float* ctab  = (float*)p;  p += 8192 * 4;
    float* stab  = (float*)p;  p += 8192 * 4;
    // q/k/v are indexed by ((bu*8+h)*512+a)*32+d -> 512*512*32 = TOK*256 elems!
    bf16_t* qbf  = (bf16_t*)p; p += (size_t)TOK * 256 * 2;
    bf16_t* kbf  = (bf16_t*)p; p += (size_t)TOK * 256 * 2;
    bf16_t* vbf  = (bf16_t*)p; p += (size_t)TOK * 256 * 2;
    bf16_t* abuf = (bf16_t*)p; p += (size_t)TOK * 256 * 2;

    const bf16_t* Wqkv = Wall;
    const bf16_t* Wo   = Wall + (size_t)768 * 256;
    const bf16_t* W1   = Wall + (size_t)1024 * 256;
    const bf16_t* W2   = Wall + (size_t)1280 * 256;

    setup_kernel<<<1664, 64, 0, stream>>>(proj_v, proj_g, ff_v, ff_g,
                                          w1_v, w1_g, w2_v, w2_g,
                                          Wall, ctab, stab);
    qkv_kernel<<<TOK / 64, 256, 0, stream>>>(z, ln1_g, ln1_b, Wqkv, proj_b,
                                             ctab, stab, qbf, kbf, vbf);
    attn_kernel<<<64 * 8, 512, 0, stream>>>(qbf, kbf, vbf, abuf);
    tail_kernel<<<TOK / 64, 256, 0, stream>>>(abuf, Wo, ff_b, z, ln2_g, ln2_b,
                                              W1, w1_b, W2, w2_b, out);
}

// Round 5
// 285.987 us; speedup vs baseline: 3.7040x; 1.1301x over previous
//
#include <hip/hip_runtime.h>
#include <cmath>

#define EMB 256
#define NHEAD 8
#define HD 32
#define A_LEN 512
#define TOK 32768

typedef __bf16 bf16_t;
typedef __bf16 bf16x8 __attribute__((ext_vector_type(8)));
typedef __bf16 bf16x4 __attribute__((ext_vector_type(4)));
typedef float floatx4 __attribute__((ext_vector_type(4)));

#define MFMA16(a, b, c) __builtin_amdgcn_mfma_f32_16x16x32_bf16((a), (b), (c), 0, 0, 0)

// ---------------------------------------------------------------------------
// Setup: weight_norm all 4 weights -> bf16 rows in Wall, plus RoPE cos/sin
// tables. Blocks 0..1535: one wave per weight row. Blocks 1536..1663: table.
// ---------------------------------------------------------------------------
__global__ __launch_bounds__(64) void setup_kernel(
    const float* __restrict__ proj_v, const float* __restrict__ proj_g,
    const float* __restrict__ ff_v, const float* __restrict__ ff_g,
    const float* __restrict__ w1_v, const float* __restrict__ w1_g,
    const float* __restrict__ w2_v, const float* __restrict__ w2_g,
    bf16_t* __restrict__ Wall, float* __restrict__ ctab,
    float* __restrict__ stab) {
    int b = blockIdx.x;
    int lane = threadIdx.x;
    if (b < 1536) {
        const float* v; const float* g; int r;
        if (b < 768)       { v = proj_v; g = proj_g; r = b; }
        else if (b < 1024) { v = ff_v;   g = ff_g;   r = b - 768; }
        else if (b < 1280) { v = w1_v;   g = w1_g;   r = b - 1024; }
        else               { v = w2_v;   g = w2_g;   r = b - 1280; }
        const floatx4* vr = (const floatx4*)(v + (size_t)r * 256);
        floatx4 x = vr[lane];
        float ss = x[0] * x[0] + x[1] * x[1] + x[2] * x[2] + x[3] * x[3];
#pragma unroll
        for (int off = 32; off >= 1; off >>= 1) ss += __shfl_xor(ss, off);
        float sc = g[r] * rsqrtf(ss);
        bf16x4 o;
        o[0] = (bf16_t)(x[0] * sc); o[1] = (bf16_t)(x[1] * sc);
        o[2] = (bf16_t)(x[2] * sc); o[3] = (bf16_t)(x[3] * sc);
        ((bf16x4*)(Wall + (size_t)b * 256))[lane] = o;
    } else {
        int idx = (b - 1536) * 64 + lane;     // 0..8191 = a*16 + i
        int a = idx >> 4, i = idx & 15;
        float freq = expf(-(float)(2 * i) * 0.2878231366242558f); // ln(1e4)/32
        float ang = (float)a * freq;
        ctab[idx] = cosf(ang);
        stab[idx] = sinf(ang);
    }
}

// ---------------------------------------------------------------------------
// QKV: LN1 -> bf16 xn (LDS) -> MFMA GEMM vs Wqkv[768][256] -> bias -> RoPE ->
// q (pre-scaled 1/sqrt(32)) and k to [bh][a][d]; v transposed through LDS to
// global [bh][d][a] so attention can stage V^T with straight vector copies.
// ---------------------------------------------------------------------------
__global__ __launch_bounds__(256, 2) void qkv_kernel(
    const float* __restrict__ z, const float* __restrict__ ln_g,
    const float* __restrict__ ln_b, const bf16_t* __restrict__ W,
    const float* __restrict__ pb, const float* __restrict__ ctab,
    const float* __restrict__ stab, bf16_t* __restrict__ qbf,
    bf16_t* __restrict__ kbf, bf16_t* __restrict__ vtb) {
    __shared__ bf16_t xns[64 * 264];   // 33.8 KB
    __shared__ bf16_t vls[256 * 72];   // 36.9 KB, v^T staging [vcol][a_loc]
    int tid = threadIdx.x;
    int t0 = blockIdx.x * 64;

#pragma unroll
    for (int it = 0; it < 4; ++it) {
        int row = it * 16 + (tid >> 4);
        int sub = tid & 15;
        const floatx4* zr = (const floatx4*)(z + (size_t)(t0 + row) * 256 + sub * 16);
        floatx4 v0 = zr[0], v1 = zr[1], v2 = zr[2], v3 = zr[3];
        float vals[16];
        ((floatx4*)vals)[0] = v0; ((floatx4*)vals)[1] = v1;
        ((floatx4*)vals)[2] = v2; ((floatx4*)vals)[3] = v3;
        float s = 0.f, q2 = 0.f;
#pragma unroll
        for (int i = 0; i < 16; ++i) { s += vals[i]; q2 += vals[i] * vals[i]; }
#pragma unroll
        for (int off = 8; off >= 1; off >>= 1) {
            s += __shfl_xor(s, off);
            q2 += __shfl_xor(q2, off);
        }
        float mu = s * (1.f / 256.f);
        float inv = rsqrtf(q2 * (1.f / 256.f) - mu * mu + 1e-5f);
        int cb = sub * 16;
        bf16x8 o0, o1;
#pragma unroll
        for (int i = 0; i < 8; ++i)
            o0[i] = (bf16_t)((vals[i] - mu) * inv * ln_g[cb + i] + ln_b[cb + i]);
#pragma unroll
        for (int i = 0; i < 8; ++i)
            o1[i] = (bf16_t)((vals[8 + i] - mu) * inv * ln_g[cb + 8 + i] + ln_b[cb + 8 + i]);
        *(bf16x8*)&xns[row * 264 + cb] = o0;
        *(bf16x8*)&xns[row * 264 + cb + 8] = o1;
    }
    __syncthreads();

    int wv = tid >> 6, lane = tid & 63, quad = lane >> 4, lidx = lane & 15;

    bf16x8 afr[4][8];
#pragma unroll
    for (int mt = 0; mt < 4; ++mt)
#pragma unroll
        for (int kc = 0; kc < 8; ++kc)
            afr[mt][kc] = *(const bf16x8*)&xns[(mt * 16 + lidx) * 264 + kc * 32 + quad * 8];

#pragma unroll 1
    for (int nt = 0; nt < 12; ++nt) {
        int nbase = wv * 192 + nt * 16;
        int n = nbase + lidx;
        bf16x8 bfr[8];
#pragma unroll
        for (int kc = 0; kc < 8; ++kc)
            bfr[kc] = *(const bf16x8*)&W[(size_t)n * 256 + kc * 32 + quad * 8];
        floatx4 acc[4];
#pragma unroll
        for (int mt = 0; mt < 4; ++mt) acc[mt] = (floatx4){0.f, 0.f, 0.f, 0.f};
#pragma unroll
        for (int kc = 0; kc < 8; ++kc)
#pragma unroll
            for (int mt = 0; mt < 4; ++mt)
                acc[mt] = MFMA16(afr[mt][kc], bfr[kc], acc[mt]);

        float bias = pb[n];
        int htile = nbase / 96;
        int rem = nbase % 96;
        int sec = rem >> 5;               // 0=q 1=k 2=v (tiles never straddle)
        int d = (rem & 31) + lidx;
#pragma unroll
        for (int mt = 0; mt < 4; ++mt) {
#pragma unroll
            for (int r = 0; r < 4; ++r) {
                int tok = t0 + mt * 16 + quad * 4 + r;
                int a = tok & 511;
                int bu = tok >> 9;
                float val = acc[mt][r] + bias;
                if (sec == 2) {
                    int a_loc = mt * 16 + quad * 4 + r;
                    vls[(htile * 32 + d) * 72 + a_loc] = (bf16_t)val;
                } else {
                    size_t addr = ((size_t)((bu * 8 + htile) * 512 + a)) * 32 + d;
                    float part = __shfl_xor(val, 1);
                    float cs = ctab[a * 16 + (d >> 1)];
                    float sn = stab[a * 16 + (d >> 1)];
                    float res = ((d & 1) == 0) ? (val * cs - part * sn)
                                               : (val * cs + part * sn);
                    if (sec == 0)
                        qbf[addr] = (bf16_t)(res * 0.17677669529663687f);
                    else
                        kbf[addr] = (bf16_t)res;
                }
            }
        }
    }
    __syncthreads();
    // flush v^T: vcol = tid -> global row bu*256 + vcol, cols a0..a0+63
    {
        int bu = t0 >> 9, a0 = t0 & 511;
        size_t gbase = ((size_t)(bu * 256 + tid)) * 512 + a0;
#pragma unroll
        for (int j = 0; j < 8; ++j)
            *(bf16x8*)&vtb[gbase + j * 8] = *(const bf16x8*)&vls[tid * 72 + j * 8];
    }
}

// ---------------------------------------------------------------------------
// Attention: one block (512 thr = 8 waves) per (bu,h). No online max (scores
// bounded; exp(s-8) via MFMA C-init, softmax shift-invariant -> exact).
// LDS exactly 80 KB (2 blocks/CU): K [512][32] ^(key&3) swizzle, V^T
// [32][512] ^(row&7) swizzle, P [16][64]/wave ^(row&7) swizzle. Zero in-loop
// barriers; P round-trips wave-private.
// ---------------------------------------------------------------------------
__global__ __launch_bounds__(512, 4) void attn_kernel(
    const bf16_t* __restrict__ qbf, const bf16_t* __restrict__ kbf,
    const bf16_t* __restrict__ vtb, bf16_t* __restrict__ ob) {
    __shared__ bf16_t Kls[512 * 32];      // 32 KB
    __shared__ bf16_t Vt[32 * 512];       // 32 KB
    __shared__ bf16_t Pls[8 * 16 * 64];   // 16 KB
    int tid = threadIdx.x;
    int wv = tid >> 6, lane = tid & 63, quad = lane >> 4, lidx = lane & 15;
    int bh = blockIdx.x;
    int bu = bh >> 3, h = bh & 7;
    size_t hb = (size_t)bh * (A_LEN * HD);

    // ---- stage K (row-swizzled) and V^T (pre-transposed in global) ----
#pragma unroll
    for (int i = 0; i < 4; ++i) {
        int c = tid + i * 512;            // 16B chunk id, 0..2047
        int key = c >> 2, blk = c & 3;
        bf16x8 kv = *(const bf16x8*)&kbf[hb + (size_t)c * 8];
        *(bf16x8*)&Kls[key * 32 + ((blk ^ (key & 3)) << 3)] = kv;
        int vrow = c >> 6, vblk = c & 63;
        bf16x8 vv = *(const bf16x8*)&vtb[hb + (size_t)c * 8];
        *(bf16x8*)&Vt[vrow * 512 + ((vblk ^ (vrow & 7)) << 3)] = vv;
    }
    __syncthreads();

    int pbase = wv * (16 * 64);
    const floatx4 cm8 = (floatx4){-8.f, -8.f, -8.f, -8.f};
    const floatx4 zero4 = (floatx4){0.f, 0.f, 0.f, 0.f};

#pragma unroll 1
    for (int mt = 0; mt < 4; ++mt) {
        int q0 = wv * 64 + mt * 16;
        bf16x8 qfrag = *(const bf16x8*)&qbf[hb + (size_t)(q0 + lidx) * 32 + quad * 8];
        float l_[4] = {0.f, 0.f, 0.f, 0.f};
        floatx4 Oacc[2];
        Oacc[0] = zero4; Oacc[1] = zero4;

#pragma unroll 1
        for (int kc = 0; kc < 8; ++kc) {
            floatx4 sc[4];
#pragma unroll
            for (int t = 0; t < 4; ++t) {
                bf16x8 kf = *(const bf16x8*)&Kls[(kc * 64 + t * 16 + lidx) * 32 +
                                                 ((quad ^ (lidx & 3)) << 3)];
                sc[t] = MFMA16(qfrag, kf, cm8);   // s - 8 folded into C
            }
            float p[4][4];
#pragma unroll
            for (int t = 0; t < 4; ++t)
#pragma unroll
                for (int r = 0; r < 4; ++r) p[t][r] = __expf(sc[t][r]);
            // store P (C-layout -> swizzled [row][col])
#pragma unroll
            for (int t = 0; t < 4; ++t)
#pragma unroll
                for (int r = 0; r < 4; ++r) {
                    int row = quad * 4 + r;
                    int pc = (t * 16 + lidx) ^ ((row & 7) << 3);
                    Pls[pbase + row * 64 + pc] = (bf16_t)p[t][r];
                }
            // row sums (4 independent shuffle chains)
#pragma unroll
            for (int r = 0; r < 4; ++r) {
                float s = (p[0][r] + p[1][r]) + (p[2][r] + p[3][r]);
#pragma unroll
                for (int off = 8; off >= 1; off >>= 1) s += __shfl_xor(s, off);
                l_[r] += s;
            }
            // PV
#pragma unroll
            for (int ks = 0; ks < 2; ++ks) {
                bf16x8 pf = *(const bf16x8*)&Pls[pbase + lidx * 64 +
                                                 (((ks * 4 + quad) ^ (lidx & 7)) << 3)];
#pragma unroll
                for (int nt = 0; nt < 2; ++nt) {
                    int vrow = nt * 16 + lidx;
                    bf16x8 vf = *(const bf16x8*)&Vt[vrow * 512 +
                        ((kc * 8 + ((ks * 4 + quad) ^ (lidx & 7))) << 3)];
                    Oacc[nt] = MFMA16(pf, vf, Oacc[nt]);
                }
            }
        }
#pragma unroll
        for (int nt = 0; nt < 2; ++nt)
#pragma unroll
            for (int r = 0; r < 4; ++r) {
                int tok = bu * 512 + q0 + quad * 4 + r;
                ob[(size_t)tok * 256 + h * 32 + nt * 16 + lidx] =
                    (bf16_t)(Oacc[nt][r] / l_[r]);
            }
    }
}

// ---------------------------------------------------------------------------
// Fused tail: out = r1 + FFN(LN2(r1)),  r1 = z + attn@Wo^T + ff_b.
// ---------------------------------------------------------------------------
__global__ __launch_bounds__(256, 2) void tail_kernel(
    const bf16_t* __restrict__ X, const bf16_t* __restrict__ Wo,
    const float* __restrict__ obias, const float* __restrict__ zin,
    const float* __restrict__ ln_g, const float* __restrict__ ln_b,
    const bf16_t* __restrict__ W1, const float* __restrict__ b1,
    const bf16_t* __restrict__ W2, const float* __restrict__ b2,
    float* __restrict__ outp) {
    __shared__ bf16_t xns[64 * 264];   // 33.8 KB
    __shared__ bf16_t hs[64 * 264];    // 33.8 KB
    __shared__ float red[64 * 8];
    __shared__ float mi[64 * 2];
    int tid = threadIdx.x;
    int t0 = blockIdx.x * 64;
    int wv = tid >> 6, lane = tid & 63, quad = lane >> 4, lidx = lane & 15;

    bf16x8 afr[4][8];
#pragma unroll
    for (int mt = 0; mt < 4; ++mt)
#pragma unroll
        for (int kc = 0; kc < 8; ++kc)
            afr[mt][kc] = *(const bf16x8*)&X[(size_t)(t0 + mt * 16 + lidx) * 256 + kc * 32 + quad * 8];

    float r1[4][4][4];   // [nt][mt][r]
#pragma unroll 1
    for (int nt = 0; nt < 4; ++nt) {
        int n = wv * 64 + nt * 16 + lidx;
        bf16x8 bfr[8];
#pragma unroll
        for (int kc = 0; kc < 8; ++kc)
            bfr[kc] = *(const bf16x8*)&Wo[(size_t)n * 256 + kc * 32 + quad * 8];
        floatx4 acc[4];
#pragma unroll
        for (int mt = 0; mt < 4; ++mt) acc[mt] = (floatx4){0.f, 0.f, 0.f, 0.f};
#pragma unroll
        for (int kc = 0; kc < 8; ++kc)
#pragma unroll
            for (int mt = 0; mt < 4; ++mt)
                acc[mt] = MFMA16(afr[mt][kc], bfr[kc], acc[mt]);
        float b = obias[n];
#pragma unroll
        for (int mt = 0; mt < 4; ++mt)
#pragma unroll
            for (int r = 0; r < 4; ++r) {
                size_t o = (size_t)(t0 + mt * 16 + quad * 4 + r) * 256 + n;
                r1[nt][mt][r] = zin[o] + acc[mt][r] + b;
            }
    }

#pragma unroll
    for (int mt = 0; mt < 4; ++mt)
#pragma unroll
        for (int r = 0; r < 4; ++r) {
            float s = 0.f, ss = 0.f;
#pragma unroll
            for (int nt = 0; nt < 4; ++nt) {
                float v = r1[nt][mt][r];
                s += v; ss += v * v;
            }
#pragma unroll
            for (int off = 8; off >= 1; off >>= 1) {
                s += __shfl_xor(s, off);
                ss += __shfl_xor(ss, off);
            }
            if (lidx == 0) {
                int row = mt * 16 + quad * 4 + r;
                red[row * 8 + wv * 2] = s;
                red[row * 8 + wv * 2 + 1] = ss;
            }
        }
    __syncthreads();
    if (tid < 64) {
        float s = 0.f, ss = 0.f;
#pragma unroll
        for (int w = 0; w < 4; ++w) {
            s += red[tid * 8 + w * 2];
            ss += red[tid * 8 + w * 2 + 1];
        }
        float mu = s * (1.f / 256.f);
        mi[tid * 2] = mu;
        mi[tid * 2 + 1] = rsqrtf(ss * (1.f / 256.f) - mu * mu + 1e-5f);
    }
    __syncthreads();

    float gv[4], bv[4];
#pragma unroll
    for (int nt = 0; nt < 4; ++nt) {
        int n = wv * 64 + nt * 16 + lidx;
        gv[nt] = ln_g[n]; bv[nt] = ln_b[n];
    }
#pragma unroll
    for (int mt = 0; mt < 4; ++mt)
#pragma unroll
        for (int r = 0; r < 4; ++r) {
            int row = mt * 16 + quad * 4 + r;
            float mu = mi[row * 2], inv = mi[row * 2 + 1];
#pragma unroll
            for (int nt = 0; nt < 4; ++nt) {
                int n = wv * 64 + nt * 16 + lidx;
                xns[row * 264 + n] = (bf16_t)((r1[nt][mt][r] - mu) * inv * gv[nt] + bv[nt]);
            }
        }
    __syncthreads();

#pragma unroll
    for (int mt = 0; mt < 4; ++mt)
#pragma unroll
        for (int kc = 0; kc < 8; ++kc)
            afr[mt][kc] = *(const bf16x8*)&xns[(mt * 16 + lidx) * 264 + kc * 32 + quad * 8];
#pragma unroll 1
    for (int nt = 0; nt < 4; ++nt) {
        int n = wv * 64 + nt * 16 + lidx;
        bf16x8 bfr[8];
#pragma unroll
        for (int kc = 0; kc < 8; ++kc)
            bfr[kc] = *(const bf16x8*)&W1[(size_t)n * 256 + kc * 32 + quad * 8];
        floatx4 acc[4];
#pragma unroll
        for (int mt = 0; mt < 4; ++mt) acc[mt] = (floatx4){0.f, 0.f, 0.f, 0.f};
#pragma unroll
        for (int kc = 0; kc < 8; ++kc)
#pragma unroll
            for (int mt = 0; mt < 4; ++mt)
                acc[mt] = MFMA16(afr[mt][kc], bfr[kc], acc[mt]);
        float b = b1[n];
#pragma unroll
        for (int mt = 0; mt < 4; ++mt)
#pragma unroll
            for (int r = 0; r < 4; ++r) {
                float x = acc[mt][r] + b;
                float gel = 0.5f * x * (1.f + erff(x * 0.7071067811865476f));
                hs[(mt * 16 + quad * 4 + r) * 264 + n] = (bf16_t)gel;
            }
    }
    __syncthreads();

#pragma unroll
    for (int mt = 0; mt < 4; ++mt)
#pragma unroll
        for (int kc = 0; kc < 8; ++kc)
            afr[mt][kc] = *(const bf16x8*)&hs[(mt * 16 + lidx) * 264 + kc * 32 + quad * 8];
#pragma unroll 1
    for (int nt = 0; nt < 4; ++nt) {
        int n = wv * 64 + nt * 16 + lidx;
        bf16x8 bfr[8];
#pragma unroll
        for (int kc = 0; kc < 8; ++kc)
            bfr[kc] = *(const bf16x8*)&W2[(size_t)n * 256 + kc * 32 + quad * 8];
        floatx4 acc[4];
#pragma unroll
        for (int mt = 0; mt < 4; ++mt) acc[mt] = (floatx4){0.f, 0.f, 0.f, 0.f};
#pragma unroll
        for (int kc = 0; kc < 8; ++kc)
#pragma unroll
            for (int mt = 0; mt < 4; ++mt)
                acc[mt] = MFMA16(afr[mt][kc], bfr[kc], acc[mt]);
        float b = b2[n];
#pragma unroll
        for (int mt = 0; mt < 4; ++mt)
#pragma unroll
            for (int r = 0; r < 4; ++r) {
                size_t o = (size_t)(t0 + mt * 16 + quad * 4 + r) * 256 + n;
                outp[o] = r1[nt][mt][r] + acc[mt][r] + b;
            }
    }
}

// ---------------------------------------------------------------------------
extern "C" void kernel_launch(void* const* d_in, const int* in_sizes, int n_in,
                              void* d_out, int out_size, void* d_ws, size_t ws_size,
                              hipStream_t stream) {
    const float* z      = (const float*)d_in[0];
    const float* ln1_g  = (const float*)d_in[1];
    const float* ln1_b  = (const float*)d_in[2];
    const float* proj_v = (const float*)d_in[3];
    const float* proj_g = (const float*)d_in[4];
    const float* proj_b = (const float*)d_in[5];
    const float* ff_v   = (const float*)d_in[6];
    const float* ff_g   = (const float*)d_in[7];
    const float* ff_b   = (const float*)d_in[8];
    const float* ln2_g  = (const float*)d_in[9];
    const float* ln2_b  = (const float*)d_in[10];
    const float* w1_v   = (const float*)d_in[11];
    const float* w1_g   = (const float*)d_in[12];
    const float* w1_b   = (const float*)d_in[13];
    const float* w2_v   = (const float*)d_in[14];
    const float* w2_g   = (const float*)d_in[15];
    const float* w2_b   = (const float*)d_in[16];
    float* out = (float*)d_out;

    char* p = (char*)d_ws;
    bf16_t* Wall = (bf16_t*)p; p += (size_t)1536 * 256 * 2;
    float* ctab  = (float*)p;  p += 8192 * 4;
    float* stab  = (float*)p;  p += 8192 * 4;
    // q/k: [bh][a][d]; vtb: [bh][d][a]; each 512*512*32 = TOK*256 elems
    bf16_t* qbf  = (bf16_t*)p; p += (size_t)TOK * 256 * 2;
    bf16_t* kbf  = (bf16_t*)p; p += (size_t)TOK * 256 * 2;
    bf16_t* vtb  = (bf16_t*)p; p += (size_t)TOK * 256 * 2;
    bf16_t* abuf = (bf16_t*)p; p += (size_t)TOK * 256 * 2;

    const bf16_t* Wqkv = Wall;
    const bf16_t* Wo   = Wall + (size_t)768 * 256;
    const bf16_t* W1   = Wall + (size_t)1024 * 256;
    const bf16_t* W2   = Wall + (size_t)1280 * 256;

    setup_kernel<<<1664, 64, 0, stream>>>(proj_v, proj_g, ff_v, ff_g,
                                          w1_v, w1_g, w2_v, w2_g,
                                          Wall, ctab, stab);
    qkv_kernel<<<TOK / 64, 256, 0, stream>>>(z, ln1_g, ln1_b, Wqkv, proj_b,
                                             ctab, stab, qbf, kbf, vtb);
    attn_kernel<<<64 * 8, 512, 0, stream>>>(qbf, kbf, vtb, abuf);
    tail_kernel<<<TOK / 64, 256, 0, stream>>>(abuf, Wo, ff_b, z, ln2_g, ln2_b,
                                              W1, w1_b, W2, w2_b, out);
}